// Round 7
// baseline (263.216 us; speedup 1.0000x reference)
//
#include <hip/hip_runtime.h>

// CASSI forward A^T(A(x)) — R6: fused quad-column (float4) formulation.
//
// out[b,l,m,n] = phi[l,m,n] * y2[b,m,n+2l]
// y2[b,m,c]    = sum_l phi[l,m,c-2l] * x[b,l,m,c-2l]   (valid 0<=c-2l<N)
//
// Ladder so far (same bytes each round):
//  R1 4B accesses, plain st : 100 µs
//  R2 8B accesses, nt st    :  81 µs   <- widening VMEM paid 1.23x
//  R4 8B accesses, plain st : 109 µs   <- nt protects x L3-residency
//  R5 split read/write kern :  83 µs   <- losing read/write overlap = null
// R6: 16B accesses, nt st, fused. One thread owns 4 dispersed columns
// (c0=4p, n0=c0-2l even -> 8B-aligned float4 per band). x batched in two
// 14-band half-batches (56 VGPR in flight, same x-bytes/wave as R2, half
// the instructions). phi NOT kept to phase 2 (re-load hits L1/L2) so VGPR
// stays ~100 -> 5 waves/SIMD, avoiding R3's register collapse.
// Edge quads (n0==-2 or 254; <=2 of 28 bands/thread) take a float2 path.

constexpr int L_BANDS = 28;
constexpr int M_DIM   = 256;
constexpr int N_DIM   = 256;
constexpr int SHIFT   = 2;
constexpr int N_OUT   = N_DIM + SHIFT * (L_BANDS - 1);  // 310
constexpr int NQUAD   = 78;                             // ceil(310/4) quads/row
constexpr int MN      = M_DIM * N_DIM;                  // 65536
constexpr int HALF    = L_BANDS / 2;                    // 14

typedef float v2f __attribute__((ext_vector_type(2), aligned(4)));
typedef float v4f __attribute__((ext_vector_type(4), aligned(4)));

__global__ __launch_bounds__(320) void cassi_fwd_kernel(
    const float* __restrict__ x,
    const float* __restrict__ phi,
    float* __restrict__ out)
{
    const int t = threadIdx.x;
    const int r = t / 80;               // 0..3: row within block
    const int p = t - 80 * r;           // quad index within the row
    if (p >= NQUAD) return;             // 2 idle lanes per 80 (no barriers)

    const int b  = blockIdx.x >> 6;                 // / (M_DIM/4)
    const int m  = ((blockIdx.x & 63) << 2) + r;    // 4*(blk%64) + r
    const int c0 = p << 2;                          // first dispersed column

    const float* xb = x   + b * (L_BANDS * MN) + m * N_DIM;  // x[b, 0, m, 0]
    const float* pb = phi +                      m * N_DIM;  // phi[0, m, 0]
    float*       ob = out + b * (L_BANDS * MN) + m * N_DIM;  // out[b, 0, m, 0]

    v4f acc = (v4f)(0.0f);
    v4f xr[HALF];

    // ---- Phase 1: two half-batches. Issue 14 x-quad loads (56 VGPR in
    // flight), then stream phi quads into the FMA as they arrive. ----
    #pragma unroll
    for (int h = 0; h < 2; ++h) {
        #pragma unroll
        for (int i = 0; i < HALF; ++i) {
            const int l  = h * HALF + i;
            const int n0 = c0 - SHIFT * l;              // even
            if (n0 >= 0 && n0 <= N_DIM - 4) {
                xr[i] = *(const v4f*)(xb + l * MN + n0);
            } else if (n0 == -2) {                      // lanes 2,3 valid (n=0,1)
                const v2f a = *(const v2f*)(xb + l * MN);
                xr[i] = (v4f){0.0f, 0.0f, a.x, a.y};
            } else if (n0 == N_DIM - 2) {               // lanes 0,1 valid
                const v2f a = *(const v2f*)(xb + l * MN + (N_DIM - 2));
                xr[i] = (v4f){a.x, a.y, 0.0f, 0.0f};
            } else {
                xr[i] = (v4f)(0.0f);
            }
        }
        #pragma unroll
        for (int i = 0; i < HALF; ++i) {
            const int l  = h * HALF + i;
            const int n0 = c0 - SHIFT * l;
            v4f pv;
            if (n0 >= 0 && n0 <= N_DIM - 4) {
                pv = *(const v4f*)(pb + l * MN + n0);
            } else if (n0 == -2) {
                const v2f a = *(const v2f*)(pb + l * MN);
                pv = (v4f){0.0f, 0.0f, a.x, a.y};
            } else if (n0 == N_DIM - 2) {
                const v2f a = *(const v2f*)(pb + l * MN + (N_DIM - 2));
                pv = (v4f){a.x, a.y, 0.0f, 0.0f};
            } else {
                pv = (v4f)(0.0f);
            }
            acc += xr[i] * pv;
        }
    }

    // ---- Phase 2: reload phi (L1/L2 hit), multiply by y2, nt store. ----
    #pragma unroll
    for (int l = 0; l < L_BANDS; ++l) {
        const int n0 = c0 - SHIFT * l;
        if (n0 >= 0 && n0 <= N_DIM - 4) {
            const v4f pv = *(const v4f*)(pb + l * MN + n0);
            __builtin_nontemporal_store(pv * acc, (v4f*)(ob + l * MN + n0));
        } else if (n0 == -2) {
            const v2f a = *(const v2f*)(pb + l * MN);
            const v2f o = {a.x * acc.z, a.y * acc.w};
            __builtin_nontemporal_store(o, (v2f*)(ob + l * MN));
        } else if (n0 == N_DIM - 2) {
            const v2f a = *(const v2f*)(pb + l * MN + (N_DIM - 2));
            const v2f o = {a.x * acc.x, a.y * acc.y};
            __builtin_nontemporal_store(o, (v2f*)(ob + l * MN + (N_DIM - 2)));
        }
    }
}

extern "C" void kernel_launch(void* const* d_in, const int* in_sizes, int n_in,
                              void* d_out, int out_size, void* d_ws, size_t ws_size,
                              hipStream_t stream) {
    const float* x   = (const float*)d_in[0];
    const float* phi = (const float*)d_in[1];
    float*       out = (float*)d_out;

    const int B = in_sizes[0] / (L_BANDS * MN);   // 32

    dim3 grid(B * (M_DIM / 4));  // one block per (b, 4-row group): 2048 blocks
    dim3 block(320);             // 4 rows x 80 (78 active quad-threads)
    cassi_fwd_kernel<<<grid, block, 0, stream>>>(x, phi, out);
}

// Round 8
// 101.272 us; speedup vs baseline: 2.5991x; 2.5991x over previous
//
#include <hip/hip_runtime.h>

// CASSI forward A^T(A(x)) — R7: fused; R2 float2 register gather +
// LDS y2 exchange + band-per-wave ALIGNED float4 nontemporal stores.
//
// out[b,l,m,n] = phi[l,m,n] * y2[b,m,n+2l]
// y2[b,m,c]    = sum_l phi[l,m,c-2l] * x[b,l,m,c-2l]   (valid 0<=c-2l<N)
//
// Evidence ladder:
//  R2 8B gather + 8B nt st : 81 µs, WRITE 253MB (+10% partial sectors)
//  R3 LDS + plain 16B st   : 121 µs (plain st thrash + de-pipelined loads)
//  R4 plain 8B st          : 109 µs (nt protects x L3 residency: keep nt)
//  R6 misaligned 16B nt st : 263 µs (WRITE 377MB — nt MUST be sector-aligned)
// R7 fixes R3's two failure modes:
//  * nt kept (writes bypass L3 so x+phi=242MB stays resident),
//  * sched_barrier(0) after the x-load loop pins all 28 float2 x-loads
//    in flight (R3's compiler re-schedule collapsed VGPR 88->64),
//  * phi streamed into the FMAs (not kept in regs) — phase 2 re-reads phi
//    from L1/L2 (same lines just touched; per-XCD L2-resident since
//    blockIdx%8 == m-group%8 pins equal-m blocks to one XCD).
// Phase 2: wave w handles (row, band) units; 64 lanes x float4 = one full
// 1KB aligned band row per unit -> WRITE_SIZE exactly 229.4MB.

constexpr int L_BANDS = 28;
constexpr int M_DIM   = 256;
constexpr int N_DIM   = 256;
constexpr int SHIFT   = 2;
constexpr int N_OUT   = N_DIM + SHIFT * (L_BANDS - 1);  // 310
constexpr int NPAIR   = N_OUT / 2;                      // 155
constexpr int MN      = M_DIM * N_DIM;                  // 65536
constexpr int Y2PAD   = 352;                            // swz(309)=347 < 352
constexpr int UNITS   = 2 * L_BANDS;                    // 56 (row,band) units

typedef float v2f __attribute__((ext_vector_type(2)));
typedef float v4f __attribute__((ext_vector_type(4)));

// LDS skew: phase-2 reads stride 4 words/lane (8-way on 32 banks unswizzled);
// +w/8 spreads to ~2-way (free per m136). Even pairs stay adjacent, so
// phase-1's y2 pair write is two adjacent b32 writes.
__device__ __forceinline__ int swz(int w) { return w + (w >> 3); }

__global__ __launch_bounds__(320) void cassi_fwd_kernel(
    const float* __restrict__ x,
    const float* __restrict__ phi,
    float* __restrict__ out)
{
    __shared__ float y2s[2][Y2PAD];

    const int t  = threadIdx.x;
    const int b  = blockIdx.x >> 7;          // / (M_DIM/2)
    const int m0 = (blockIdx.x & 127) << 1;  // first of the block's 2 rows

    // ---------------- Phase 1: gather x*phi -> y2 (LDS) ----------------
    {
        const int r = (t >= 160) ? 1 : 0;
        const int p = t - 160 * r;
        if (p < NPAIR) {
            const int m  = m0 + r;
            const int c0 = p << 1;           // even dispersed column
            const float* xb = x   + b * (L_BANDS * MN) + m * N_DIM;
            const float* pb = phi +                      m * N_DIM;

            v2f xr[L_BANDS];
            #pragma unroll
            for (int l = 0; l < L_BANDS; ++l) {
                const int n0 = c0 - SHIFT * l;              // even
                xr[l] = ((unsigned)n0 < (unsigned)(N_DIM - 1))
                      ? *(const v2f*)(xb + l * MN + n0)
                      : (v2f)(0.0f);
            }
            // Pin: all 28 x-loads issued before any phi-load/FMA is scheduled.
            __builtin_amdgcn_sched_barrier(0);

            v2f acc = (v2f)(0.0f);
            #pragma unroll
            for (int l = 0; l < L_BANDS; ++l) {
                const int n0 = c0 - SHIFT * l;
                if ((unsigned)n0 < (unsigned)(N_DIM - 1)) {
                    const v2f pv = *(const v2f*)(pb + l * MN + n0);
                    acc += xr[l] * pv;
                }
            }
            const int s = swz(c0);           // swz keeps even pairs adjacent
            y2s[r][s]     = acc.x;
            y2s[r][s + 1] = acc.y;
        }
    }
    __syncthreads();

    // ------- Phase 2: out = phi * gather(y2); aligned float4 nt stores ------
    const int wid = t >> 6;        // 5 waves
    const int q   = t & 63;
    const int n0  = q << 2;        // 16B-aligned quad base
    const float* pbase = phi + m0 * N_DIM + n0;
    float*       obase = out + b * (L_BANDS * MN) + m0 * N_DIM + n0;

    #pragma unroll
    for (int it = 0; it < 12; ++it) {
        const int u = wid + it * 5;          // (row,band) unit
        if (u < UNITS) {
            const int rr = (u >= L_BANDS) ? 1 : 0;
            const int l  = u - L_BANDS * rr;
            const int w  = n0 + SHIFT * l;   // dispersed col of n0
            const v4f p4 = *(const v4f*)(pbase + l * MN + rr * N_DIM);
            v4f y4;
            y4.x = y2s[rr][swz(w)];
            y4.y = y2s[rr][swz(w + 1)];
            y4.z = y2s[rr][swz(w + 2)];
            y4.w = y2s[rr][swz(w + 3)];
            __builtin_nontemporal_store(p4 * y4,
                                        (v4f*)(obase + l * MN + rr * N_DIM));
        }
    }
}

extern "C" void kernel_launch(void* const* d_in, const int* in_sizes, int n_in,
                              void* d_out, int out_size, void* d_ws, size_t ws_size,
                              hipStream_t stream) {
    const float* x   = (const float*)d_in[0];
    const float* phi = (const float*)d_in[1];
    float*       out = (float*)d_out;

    const int B = in_sizes[0] / (L_BANDS * MN);   // 32

    dim3 grid(B * (M_DIM / 2));  // one block per (b, row-pair): 4096 blocks
    dim3 block(320);             // phase1: 2x155 pair-threads; phase2: 5 waves
    cassi_fwd_kernel<<<grid, block, 0, stream>>>(x, phi, out);
}

// Round 9
// 90.826 us; speedup vs baseline: 2.8980x; 1.1150x over previous
//
#include <hip/hip_runtime.h>

// CASSI forward A^T(A(x)) — R8: R7 structure (LDS y2 exchange + band-per-wave
// aligned float4 nt stores) with a SELECT-FREE phase-1 load batch.
//
// out[b,l,m,n] = phi[l,m,n] * y2[b,m,n+2l]
// y2[b,m,c]    = sum_l phi[l,m,c-2l] * x[b,l,m,c-2l]   (valid 0<=c-2l<N)
//
// Evidence ladder:
//  R2 8B gather + 8B nt st : 81 µs, WRITE 253MB (wave-band segment ends are
//                            partial 64B sectors -> +10% write traffic)
//  R7 LDS + aligned 4B st  : 101 µs. WRITE exactly 229.4MB (phase 2 correct!)
//                            but phase-1 reads fell to 2.4 TB/s: the
//                            `xr[l] = valid ? load : 0` select is a consumer
//                            of each load -> compiler emitted per-load
//                            waitcnt+cndmask, serializing the batch (VGPR 64).
// R8 fix: clamp the x address (always-valid load, no select on the result);
// zero the PHI operand in the consume phase instead (garbage * 0 == 0).
// The x-load loop is now a pure run of 28 global_load_dwordx2 -> all in
// flight before the first FMA, as in R2 (which hit 4.7 TB/s mixed).

constexpr int L_BANDS = 28;
constexpr int M_DIM   = 256;
constexpr int N_DIM   = 256;
constexpr int SHIFT   = 2;
constexpr int N_OUT   = N_DIM + SHIFT * (L_BANDS - 1);  // 310
constexpr int NPAIR   = N_OUT / 2;                      // 155
constexpr int MN      = M_DIM * N_DIM;                  // 65536
constexpr int Y2PAD   = 352;                            // swz(309)=347 < 352
constexpr int UNITS   = 2 * L_BANDS;                    // 56 (row,band) units

typedef float v2f __attribute__((ext_vector_type(2)));
typedef float v4f __attribute__((ext_vector_type(4)));

// LDS skew: phase-2 reads stride ~4 words/lane; +w/8 spreads banks (~2-way,
// measured 1.9M conflict cycles total ≈ 3 µs aggregate — acceptable).
__device__ __forceinline__ int swz(int w) { return w + (w >> 3); }

__global__ __launch_bounds__(320) void cassi_fwd_kernel(
    const float* __restrict__ x,
    const float* __restrict__ phi,
    float* __restrict__ out)
{
    __shared__ float y2s[2][Y2PAD];

    const int t  = threadIdx.x;
    const int b  = blockIdx.x >> 7;          // / (M_DIM/2)
    const int m0 = (blockIdx.x & 127) << 1;  // first of the block's 2 rows

    // ---------------- Phase 1: gather x*phi -> y2 (LDS) ----------------
    {
        const int r = (t >= 160) ? 1 : 0;
        const int p = t - 160 * r;
        if (p < NPAIR) {
            const int m  = m0 + r;
            const int c0 = p << 1;           // even dispersed column
            const float* xb = x   + b * (L_BANDS * MN) + m * N_DIM;
            const float* pb = phi +                      m * N_DIM;

            // Pure load batch: clamped (always-valid) addresses, no selects.
            v2f xr[L_BANDS];
            #pragma unroll
            for (int l = 0; l < L_BANDS; ++l) {
                int n0 = c0 - SHIFT * l;
                int n0c = n0 < 0 ? 0 : (n0 > N_DIM - 2 ? N_DIM - 2 : n0);
                xr[l] = *(const v2f*)(xb + l * MN + n0c);
            }
            __builtin_amdgcn_sched_barrier(0);

            // Consume: zero the phi operand for out-of-range bands.
            v2f acc = (v2f)(0.0f);
            #pragma unroll
            for (int l = 0; l < L_BANDS; ++l) {
                const int n0 = c0 - SHIFT * l;
                const bool valid = (unsigned)n0 < (unsigned)(N_DIM - 1);
                int n0c = n0 < 0 ? 0 : (n0 > N_DIM - 2 ? N_DIM - 2 : n0);
                v2f pv = *(const v2f*)(pb + l * MN + n0c);
                pv = valid ? pv : (v2f)(0.0f);
                acc += xr[l] * pv;
            }
            const int s = swz(c0);           // even pairs stay adjacent
            y2s[r][s]     = acc.x;
            y2s[r][s + 1] = acc.y;
        }
    }
    __syncthreads();

    // ------- Phase 2: out = phi * gather(y2); aligned float4 nt stores ------
    // One (row, band) unit = one full 1KB-aligned band row (64 lanes x 16B)
    // -> WRITE_SIZE exactly ideal (verified in R7).
    const int wid = t >> 6;        // 5 waves
    const int q   = t & 63;
    const int n0  = q << 2;        // 16B-aligned quad base
    const float* pbase = phi + m0 * N_DIM + n0;
    float*       obase = out + b * (L_BANDS * MN) + m0 * N_DIM + n0;

    #pragma unroll
    for (int it = 0; it < 12; ++it) {
        const int u = wid + it * 5;          // (row,band) unit
        if (u < UNITS) {
            const int rr = (u >= L_BANDS) ? 1 : 0;
            const int l  = u - L_BANDS * rr;
            const int w  = n0 + SHIFT * l;   // dispersed col of n0
            const v4f p4 = *(const v4f*)(pbase + l * MN + rr * N_DIM);
            v4f y4;
            y4.x = y2s[rr][swz(w)];
            y4.y = y2s[rr][swz(w + 1)];
            y4.z = y2s[rr][swz(w + 2)];
            y4.w = y2s[rr][swz(w + 3)];
            __builtin_nontemporal_store(p4 * y4,
                                        (v4f*)(obase + l * MN + rr * N_DIM));
        }
    }
}

extern "C" void kernel_launch(void* const* d_in, const int* in_sizes, int n_in,
                              void* d_out, int out_size, void* d_ws, size_t ws_size,
                              hipStream_t stream) {
    const float* x   = (const float*)d_in[0];
    const float* phi = (const float*)d_in[1];
    float*       out = (float*)d_out;

    const int B = in_sizes[0] / (L_BANDS * MN);   // 32

    dim3 grid(B * (M_DIM / 2));  // one block per (b, row-pair): 4096 blocks
    dim3 block(320);             // phase1: 2x155 pair-threads; phase2: 5 waves
    cassi_fwd_kernel<<<grid, block, 0, stream>>>(x, phi, out);
}